// Round 18
// baseline (737.084 us; speedup 1.0000x reference)
//
#include <hip/hip_runtime.h>
#include <stdint.h>

#define NSUP   50000
#define NSUPP  50176      // 196 * 256
#define NQRY   2048
#define KD     512
#define BK     32
#define NKT    16         // KD / BK
#define BQ     512        // query tile rows
#define BS     256        // support tile rows

typedef __attribute__((ext_vector_type(8))) short bf16x8;
typedef __attribute__((ext_vector_type(4))) float f32x4;

__device__ __forceinline__ unsigned short f2bf(float f) {
  unsigned int u = __float_as_uint(f);
  u += 0x7FFFu + ((u >> 16) & 1u);   // round-to-nearest-even
  return (unsigned short)(u >> 16);
}

// ---- prep: fused norm + normalize + f32->bf16 (+ zero pad rows) ----
__global__ __launch_bounds__(256) void prep_kernel(
    const float* __restrict__ sup, const float* __restrict__ qry,
    unsigned short* __restrict__ s_bf, unsigned short* __restrict__ q_bf) {
  const int row  = blockIdx.x * 4 + (threadIdx.x >> 6);
  const int lane = threadIdx.x & 63;

  const float* src = nullptr;
  unsigned short* dst;
  if (row < NSUPP) {
    dst = s_bf + (size_t)row * KD;
    if (row < NSUP) src = sup + (size_t)row * KD;
  } else {
    const int r = row - NSUPP;
    dst = q_bf + (size_t)r * KD;
    src = qry + (size_t)r * KD;
  }

  if (src == nullptr) {           // zero pad support row
    bf16x8 z = {};
    *(bf16x8*)(dst + lane * 8) = z;
    return;
  }

  const float4 v0 = ((const float4*)src)[lane * 2 + 0];
  const float4 v1 = ((const float4*)src)[lane * 2 + 1];
  float ss = v0.x*v0.x + v0.y*v0.y + v0.z*v0.z + v0.w*v0.w
           + v1.x*v1.x + v1.y*v1.y + v1.z*v1.z + v1.w*v1.w;
  #pragma unroll
  for (int off = 32; off > 0; off >>= 1) ss += __shfl_xor(ss, off);
  const float inv = rsqrtf(fmaxf(ss, 1e-30f));

  bf16x8 o;
  o[0]=(short)f2bf(v0.x*inv); o[1]=(short)f2bf(v0.y*inv);
  o[2]=(short)f2bf(v0.z*inv); o[3]=(short)f2bf(v0.w*inv);
  o[4]=(short)f2bf(v1.x*inv); o[5]=(short)f2bf(v1.y*inv);
  o[6]=(short)f2bf(v1.z*inv); o[7]=(short)f2bf(v1.w*inv);
  *(bf16x8*)(dst + lane * 8) = o;
}

// ---- stage one K-tile unit (RPW rows/wave x 32 cols bf16), 8 waves ----
// Linear LDS dest; bank-swizzle via permuted GLOBAL source chunk (rule 21):
// LDS granule [row][g] holds global granule g ^ ((row>>1)&3)  (16B units).
template<int RPW>
__device__ __forceinline__ void stage_unit(const unsigned short* __restrict__ g,
                                           unsigned short* lds, int grow_base,
                                           int kt, int w, int l) {
  const int chunk = (l & 3) ^ ((l >> 3) & 3);   // ((row>>1)&3) == (l>>3)&3
  #pragma unroll
  for (int i = 0; i < RPW / 16; ++i) {
    const int rb = w * RPW + i * 16;
    const unsigned short* src = g + (size_t)(grow_base + rb + (l >> 2)) * KD
                                  + kt * BK + chunk * 8;
    unsigned short* dst = lds + rb * BK + l * 8;   // wave-uniform + lane*16B
    __builtin_amdgcn_global_load_lds(
        (const __attribute__((address_space(1))) void*)src,
        (__attribute__((address_space(3))) void*)dst, 16, 0, 0);
  }
}

// ---- GEMM: out[q][s] = dot(qn[q], sn[s])  (inputs pre-normalized) ----
// 512q x 256s tile, 8 waves (each 128s x 128q), BK=32, double-buffered
// 96 KB LDS, plain __syncthreads per K-step (R12-proven), nt epilogue.
// Rationale: caches provide no operand reuse under the 410MB store stream
// (R8/R11/R17 measured) -> minimize ZERO-REUSE staging demand instead:
// (50176/256)*2MB + (2048/512)*51.4MB = 0.62 GB vs R12's 1.64 GB.
__global__ __launch_bounds__(512, 1) void gemm_kernel(
    const unsigned short* __restrict__ S,   // [NSUPP][KD] normalized bf16
    const unsigned short* __restrict__ Q,   // [NQRY][KD]  normalized bf16
    float* __restrict__ out) {              // [NQRY][NSUP]
  extern __shared__ unsigned short sm[];    // 2*BQ*BK + 2*BS*BK ushorts
  unsigned short* Qs = sm;                  // [2][BQ][BK]
  unsigned short* Ss = sm + 2 * BQ * BK;    // [2][BS][BK]

  const int tid = threadIdx.x;
  const int w = tid >> 6, l = tid & 63;
  const int ws = w & 1, wq = w >> 1;        // wave -> (s half, q quarter)
  const int rof = l & 15, hi = l >> 4;
  const int gsw = hi ^ ((rof >> 1) & 3);    // swizzled read granule

  const int ts = blockIdx.x * BS;           // support tile base
  const int tq = blockIdx.y * BQ;           // query tile base

  f32x4 acc[8][8] = {};                     // 256 VGPR accumulator

  stage_unit<BQ/8>(Q, Qs, tq, 0, w, l);
  stage_unit<BS/8>(S, Ss, ts, 0, w, l);
  __syncthreads();

  #pragma unroll 1
  for (int t = 0; t < NKT; ++t) {
    const int cur = t & 1;
    if (t + 1 < NKT) {                      // prefetch next K-tile
      stage_unit<BQ/8>(Q, Qs + (cur ^ 1) * BQ * BK, tq, t + 1, w, l);
      stage_unit<BS/8>(S, Ss + (cur ^ 1) * BS * BK, ts, t + 1, w, l);
    }

    bf16x8 a[8], b[8];
    #pragma unroll
    for (int si = 0; si < 8; ++si) {
      const int R = ws * 128 + si * 16 + rof;
      a[si] = *(const bf16x8*)(Ss + cur * BS * BK + R * BK + gsw * 8);
    }
    #pragma unroll
    for (int qi = 0; qi < 8; ++qi) {
      const int R = wq * 128 + qi * 16 + rof;
      b[qi] = *(const bf16x8*)(Qs + cur * BQ * BK + R * BK + gsw * 8);
    }

    #pragma unroll
    for (int si = 0; si < 8; ++si)
      #pragma unroll
      for (int qi = 0; qi < 8; ++qi)
        acc[si][qi] = __builtin_amdgcn_mfma_f32_16x16x32_bf16(a[si], b[qi], acc[si][qi], 0, 0, 0);

    __syncthreads();
  }

  // ---- epilogue: D row = support (contiguous 4) -> nt dwordx4 stores ----
  #pragma unroll
  for (int si = 0; si < 8; ++si) {
    const int s = ts + ws * 128 + si * 16 + hi * 4;
    if (s < NSUP) {                          // s%4==0, NSUP%4==0 -> all-or-none
      #pragma unroll
      for (int qi = 0; qi < 8; ++qi) {
        const int q = tq + wq * 128 + qi * 16 + rof;
        __builtin_nontemporal_store(acc[si][qi],
                                    (f32x4*)(out + (size_t)q * NSUP + s));
      }
    }
  }
}

extern "C" void kernel_launch(void* const* d_in, const int* in_sizes, int n_in,
                              void* d_out, int out_size, void* d_ws, size_t ws_size,
                              hipStream_t stream) {
  const float* sup = (const float*)d_in[0];   // [50000][512] f32
  const float* qry = (const float*)d_in[1];   // [2048][512] f32
  float* out = (float*)d_out;                 // [2048][50000] f32

  char* ws = (char*)d_ws;
  unsigned short* s_bf = (unsigned short*)(ws);
  unsigned short* q_bf = (unsigned short*)(ws + (size_t)NSUPP * KD * 2);
  // ws use: 50176*512*2 + 2048*512*2 = 53.5 MB

  prep_kernel<<<(NSUPP + NQRY) / 4, 256, 0, stream>>>(sup, qry, s_bf, q_bf);

  dim3 grid(NSUPP / BS, NQRY / BQ);   // (196, 4) = 784 blocks
  const size_t lds_bytes = (2 * BQ * BK + 2 * BS * BK) * sizeof(unsigned short); // 98304
  gemm_kernel<<<grid, 512, lds_bytes, stream>>>(s_bf, q_bf, out);
}

// Round 19
// 220.844 us; speedup vs baseline: 3.3376x; 3.3376x over previous
//
#include <hip/hip_runtime.h>
#include <stdint.h>

#define NSUP   50000
#define NSUPP  50176      // 196 * 256
#define NQRY   2048
#define KD     512
#define BK     32
#define NKT    16         // KD / BK
#define BQ     256        // query tile rows
#define BS     256        // support tile rows

typedef __attribute__((ext_vector_type(8))) short bf16x8;
typedef __attribute__((ext_vector_type(4))) float f32x4;

__device__ __forceinline__ unsigned short f2bf(float f) {
  unsigned int u = __float_as_uint(f);
  u += 0x7FFFu + ((u >> 16) & 1u);   // round-to-nearest-even
  return (unsigned short)(u >> 16);
}

// ---- prep: fused norm + normalize + f32->bf16 (+ zero pad rows) ----
__global__ __launch_bounds__(256) void prep_kernel(
    const float* __restrict__ sup, const float* __restrict__ qry,
    unsigned short* __restrict__ s_bf, unsigned short* __restrict__ q_bf) {
  const int row  = blockIdx.x * 4 + (threadIdx.x >> 6);
  const int lane = threadIdx.x & 63;

  const float* src = nullptr;
  unsigned short* dst;
  if (row < NSUPP) {
    dst = s_bf + (size_t)row * KD;
    if (row < NSUP) src = sup + (size_t)row * KD;
  } else {
    const int r = row - NSUPP;
    dst = q_bf + (size_t)r * KD;
    src = qry + (size_t)r * KD;
  }

  if (src == nullptr) {           // zero pad support row
    bf16x8 z = {};
    *(bf16x8*)(dst + lane * 8) = z;
    return;
  }

  const float4 v0 = ((const float4*)src)[lane * 2 + 0];
  const float4 v1 = ((const float4*)src)[lane * 2 + 1];
  float ss = v0.x*v0.x + v0.y*v0.y + v0.z*v0.z + v0.w*v0.w
           + v1.x*v1.x + v1.y*v1.y + v1.z*v1.z + v1.w*v1.w;
  #pragma unroll
  for (int off = 32; off > 0; off >>= 1) ss += __shfl_xor(ss, off);
  const float inv = rsqrtf(fmaxf(ss, 1e-30f));

  bf16x8 o;
  o[0]=(short)f2bf(v0.x*inv); o[1]=(short)f2bf(v0.y*inv);
  o[2]=(short)f2bf(v0.z*inv); o[3]=(short)f2bf(v0.w*inv);
  o[4]=(short)f2bf(v1.x*inv); o[5]=(short)f2bf(v1.y*inv);
  o[6]=(short)f2bf(v1.z*inv); o[7]=(short)f2bf(v1.w*inv);
  *(bf16x8*)(dst + lane * 8) = o;
}

// ---- stage one K-tile unit (32 rows/wave x 32 cols bf16), 8 waves ----
// Linear LDS dest; bank-swizzle via permuted GLOBAL source chunk (rule 21):
// LDS granule [row][g] holds global granule g ^ ((row>>1)&3)  (16B units).
__device__ __forceinline__ void stage_unit(const unsigned short* __restrict__ g,
                                           unsigned short* lds, int grow_base,
                                           int kt, int w, int l) {
  const int chunk = (l & 3) ^ ((l >> 3) & 3);   // ((row>>1)&3) == (l>>3)&3
  #pragma unroll
  for (int i = 0; i < 2; ++i) {
    const int rb = w * 32 + i * 16;
    const unsigned short* src = g + (size_t)(grow_base + rb + (l >> 2)) * KD
                                  + kt * BK + chunk * 8;
    unsigned short* dst = lds + rb * BK + l * 8;   // wave-uniform + lane*16B
    __builtin_amdgcn_global_load_lds(
        (const __attribute__((address_space(1))) void*)src,
        (__attribute__((address_space(3))) void*)dst, 16, 0, 0);
  }
}

// ---- GEMM: out[q][s] = dot(qn[q], sn[s])  (inputs pre-normalized) ----
// 256q x 256s tile, 8 waves (2s x 4q; per-wave 128s x 64q -> acc = 128 VGPR,
// NO SPILL under the 2-wave/SIMD 256 budget — R18's failure mode), BK=32,
// double-buffered 64 KB LDS, __syncthreads per K-step, nt dwordx4 epilogue.
// Zero-reuse staging demand 803 MB (vs R12's 1.6 GB); cache help -> less.
__global__ __launch_bounds__(512, 2) void gemm_kernel(
    const unsigned short* __restrict__ S,   // [NSUPP][KD] normalized bf16
    const unsigned short* __restrict__ Q,   // [NQRY][KD]  normalized bf16
    float* __restrict__ out) {              // [NQRY][NSUP]
  extern __shared__ unsigned short sm[];
  unsigned short* Qs = sm;                  // [2][BQ][BK]
  unsigned short* Ss = sm + 2 * BQ * BK;    // [2][BS][BK]

  const int tid = threadIdx.x;
  const int w = tid >> 6, l = tid & 63;
  const int ws2 = w & 1, wq4 = w >> 1;      // wave -> (s half, q quarter)
  const int rof = l & 15, hi = l >> 4;
  const int gsw = hi ^ ((rof >> 1) & 3);    // swizzled read granule

  const int ts = blockIdx.x * BS;           // support tile base
  const int tq = blockIdx.y * BQ;           // query tile base

  f32x4 acc[8][4] = {};                     // 128 VGPR accumulator

  stage_unit(Q, Qs, tq, 0, w, l);
  stage_unit(S, Ss, ts, 0, w, l);
  __syncthreads();

  #pragma unroll 1
  for (int t = 0; t < NKT; ++t) {
    const int cur = t & 1;
    if (t + 1 < NKT) {                      // prefetch next K-tile
      stage_unit(Q, Qs + (cur ^ 1) * BQ * BK, tq, t + 1, w, l);
      stage_unit(S, Ss + (cur ^ 1) * BS * BK, ts, t + 1, w, l);
    }

    bf16x8 a[8], b[4];
    #pragma unroll
    for (int si = 0; si < 8; ++si) {
      const int R = ws2 * 128 + si * 16 + rof;
      a[si] = *(const bf16x8*)(Ss + cur * BS * BK + R * BK + gsw * 8);
    }
    #pragma unroll
    for (int qi = 0; qi < 4; ++qi) {
      const int R = wq4 * 64 + qi * 16 + rof;
      b[qi] = *(const bf16x8*)(Qs + cur * BQ * BK + R * BK + gsw * 8);
    }

    #pragma unroll
    for (int si = 0; si < 8; ++si)
      #pragma unroll
      for (int qi = 0; qi < 4; ++qi)
        acc[si][qi] = __builtin_amdgcn_mfma_f32_16x16x32_bf16(a[si], b[qi], acc[si][qi], 0, 0, 0);

    __syncthreads();
  }

  // ---- epilogue: D row = support (contiguous 4) -> nt dwordx4 stores ----
  #pragma unroll
  for (int si = 0; si < 8; ++si) {
    const int s = ts + ws2 * 128 + si * 16 + hi * 4;
    if (s < NSUP) {                          // s%4==0, NSUP%4==0 -> all-or-none
      #pragma unroll
      for (int qi = 0; qi < 4; ++qi) {
        const int q = tq + wq4 * 64 + qi * 16 + rof;
        __builtin_nontemporal_store(acc[si][qi],
                                    (f32x4*)(out + (size_t)q * NSUP + s));
      }
    }
  }
}

extern "C" void kernel_launch(void* const* d_in, const int* in_sizes, int n_in,
                              void* d_out, int out_size, void* d_ws, size_t ws_size,
                              hipStream_t stream) {
  const float* sup = (const float*)d_in[0];   // [50000][512] f32
  const float* qry = (const float*)d_in[1];   // [2048][512] f32
  float* out = (float*)d_out;                 // [2048][50000] f32

  char* ws = (char*)d_ws;
  unsigned short* s_bf = (unsigned short*)(ws);
  unsigned short* q_bf = (unsigned short*)(ws + (size_t)NSUPP * KD * 2);
  // ws use: 50176*512*2 + 2048*512*2 = 53.5 MB

  prep_kernel<<<(NSUPP + NQRY) / 4, 256, 0, stream>>>(sup, qry, s_bf, q_bf);

  dim3 grid(NSUPP / BS, NQRY / BQ);   // (196, 8) = 1568 blocks
  const size_t lds_bytes = (size_t)(2 * BQ * BK + 2 * BS * BK) * sizeof(unsigned short); // 65536
  gemm_kernel<<<grid, 512, lds_bytes, stream>>>(s_bf, q_bf, out);
}

// Round 20
// 202.589 us; speedup vs baseline: 3.6383x; 1.0901x over previous
//
#include <hip/hip_runtime.h>
#include <stdint.h>

#define NSUP   50000
#define NSUPP  50176      // padded to multiple of 128 (and 256)
#define NQRY   2048
#define KD     512
#define BK     32
#define NKT    16         // KD / BK

typedef __attribute__((ext_vector_type(8))) short bf16x8;
typedef __attribute__((ext_vector_type(4))) float f32x4;

__device__ __forceinline__ unsigned short f2bf(float f) {
  unsigned int u = __float_as_uint(f);
  u += 0x7FFFu + ((u >> 16) & 1u);   // round-to-nearest-even
  return (unsigned short)(u >> 16);
}

// ---- prep: fused norm + normalize + f32->bf16 (+ zero pad rows) ----
__global__ __launch_bounds__(256) void prep_kernel(
    const float* __restrict__ sup, const float* __restrict__ qry,
    unsigned short* __restrict__ s_bf, unsigned short* __restrict__ q_bf) {
  const int row  = blockIdx.x * 4 + (threadIdx.x >> 6);
  const int lane = threadIdx.x & 63;

  const float* src = nullptr;
  unsigned short* dst;
  if (row < NSUPP) {
    dst = s_bf + (size_t)row * KD;
    if (row < NSUP) src = sup + (size_t)row * KD;
  } else {
    const int r = row - NSUPP;
    dst = q_bf + (size_t)r * KD;
    src = qry + (size_t)r * KD;
  }

  if (src == nullptr) {           // zero pad row
    bf16x8 z = {};
    *(bf16x8*)(dst + lane * 8) = z;
    return;
  }

  const float4 v0 = ((const float4*)src)[lane * 2 + 0];
  const float4 v1 = ((const float4*)src)[lane * 2 + 1];
  float ss = v0.x*v0.x + v0.y*v0.y + v0.z*v0.z + v0.w*v0.w
           + v1.x*v1.x + v1.y*v1.y + v1.z*v1.z + v1.w*v1.w;
  #pragma unroll
  for (int off = 32; off > 0; off >>= 1) ss += __shfl_xor(ss, off);
  const float inv = rsqrtf(fmaxf(ss, 1e-30f));

  bf16x8 o;
  o[0]=(short)f2bf(v0.x*inv); o[1]=(short)f2bf(v0.y*inv);
  o[2]=(short)f2bf(v0.z*inv); o[3]=(short)f2bf(v0.w*inv);
  o[4]=(short)f2bf(v1.x*inv); o[5]=(short)f2bf(v1.y*inv);
  o[6]=(short)f2bf(v1.z*inv); o[7]=(short)f2bf(v1.w*inv);
  *(bf16x8*)(dst + lane * 8) = o;
}

// ---- stage one 8KB K-tile unit (128 rows x 32 cols bf16), 4 waves ----
// Linear LDS dest; bank-swizzle via permuted GLOBAL source chunk (rule 21):
// LDS granule [row][c] holds global chunk c ^ ((row>>1)&3).
__device__ __forceinline__ void stage_unit(const unsigned short* __restrict__ g,
                                           unsigned short* lds, int grow_base,
                                           int kt, int w, int l) {
  const int chunk = (l & 3) ^ ((l >> 3) & 3);   // ((row>>1)&3) == (l>>3)&3 here
  #pragma unroll
  for (int i = 0; i < 2; ++i) {
    const unsigned short* src = g + (size_t)(grow_base + i*64 + w*16 + (l>>2)) * KD
                                  + kt*BK + chunk*8;
    unsigned short* dst = lds + i*2048 + w*512;  // wave-uniform base (+lane*16B)
    __builtin_amdgcn_global_load_lds(
        (const __attribute__((address_space(1))) void*)src,
        (__attribute__((address_space(3))) void*)dst, 16, 0, 0);
  }
}

// swizzled fragment-read element offset for row R, k-granule hi (0..3)
#define SWZ_OFF(R, hi) (((hi) ^ (((R) >> 1) & 3)) * 8)

// ---- GEMM: out[q][s] = dot(q_bf[q], s_bf[s])  (inputs pre-normalized) ----
// R12 structure — measured best (201.9 us total, GEMM ~170 us):
// 128x128 tile, 4 waves (2x2), BK=32, double-buffered LDS (32 KB),
// 3 blocks/CU, support-major XCD decode, NON-TEMPORAL dwordx4 epilogue
// (nt = -50 us, the one confirmed mechanism: stops output-stream L2
// write-allocation thrash). GEMM is BW-saturated at the fill-kernel
// ceiling on its realized traffic (~680 MB fetch equilibrium + 410 MB
// write at ~6.5 TB/s).
__global__ __launch_bounds__(256, 3) void gemm_kernel(
    const unsigned short* __restrict__ S,   // [NSUPP][KD] normalized bf16
    const unsigned short* __restrict__ Q,   // [NQRY][KD]  normalized bf16
    float* __restrict__ out) {              // [NQRY][NSUP]
  __shared__ __attribute__((aligned(16))) unsigned short As[2][128][BK];
  __shared__ __attribute__((aligned(16))) unsigned short Bs[2][128][BK];

  const int tid = threadIdx.x;
  const int w = tid >> 6, l = tid & 63;
  const int wr = w >> 1, wc = w & 1;       // wave -> 64x64 quadrant
  const int rof = l & 15, hi = l >> 4;

  // support-major XCD decode: 6272 blocks = 8 XCDs x 49 stiles x 16 qtiles
  const int orig  = blockIdx.x;
  const int xcd   = orig & 7;
  const int idx   = orig >> 3;             // dispatch order within XCD
  const int stile = xcd * 49 + (idx >> 4); // support tile (slow)
  const int qtile = idx & 15;              // query tile (fast)
  const int ts = stile * 128;
  const int tq = qtile * 128;

  f32x4 acc[4][4] = {};

  // prologue: stage K-tile 0 into slot 0
  stage_unit(S, &As[0][0][0], ts, 0, w, l);
  stage_unit(Q, &Bs[0][0][0], tq, 0, w, l);
  __syncthreads();

  #pragma unroll
  for (int t = 0; t < NKT; ++t) {
    const int slot = t & 1;
    if (t + 1 < NKT) {                     // prefetch next K-tile into other slot
      stage_unit(S, &As[slot ^ 1][0][0], ts, t + 1, w, l);
      stage_unit(Q, &Bs[slot ^ 1][0][0], tq, t + 1, w, l);
    }

    bf16x8 a[4], b[4];
    #pragma unroll
    for (int i = 0; i < 4; ++i) {
      const int R = wr*64 + i*16 + rof;
      a[i] = *(const bf16x8*)&As[slot][R][SWZ_OFF(R, hi)];
    }
    #pragma unroll
    for (int i = 0; i < 4; ++i) {
      const int R = wc*64 + i*16 + rof;
      b[i] = *(const bf16x8*)&Bs[slot][R][SWZ_OFF(R, hi)];
    }

    #pragma unroll
    for (int mi = 0; mi < 4; ++mi)
      #pragma unroll
      for (int ni = 0; ni < 4; ++ni)
        acc[mi][ni] = __builtin_amdgcn_mfma_f32_16x16x32_bf16(a[mi], b[ni], acc[mi][ni], 0, 0, 0);

    __syncthreads();
  }

  // ---- epilogue: non-temporal dwordx4 stores (output never re-read) ----
  #pragma unroll
  for (int mi = 0; mi < 4; ++mi) {
    const int s = ts + wr*64 + mi*16 + hi*4;    // 4 consecutive supports
    if (s < NSUP) {                              // s%4==0, NSUP%4==0 -> all-or-none
      #pragma unroll
      for (int ni = 0; ni < 4; ++ni) {
        const int q = tq + wc*64 + ni*16 + rof;
        __builtin_nontemporal_store(acc[mi][ni],
                                    (f32x4*)(out + (size_t)q * NSUP + s));
      }
    }
  }
}

extern "C" void kernel_launch(void* const* d_in, const int* in_sizes, int n_in,
                              void* d_out, int out_size, void* d_ws, size_t ws_size,
                              hipStream_t stream) {
  const float* sup = (const float*)d_in[0];   // [50000][512] f32
  const float* qry = (const float*)d_in[1];   // [2048][512] f32
  float* out = (float*)d_out;                 // [2048][50000] f32

  char* ws = (char*)d_ws;
  unsigned short* s_bf = (unsigned short*)(ws);
  unsigned short* q_bf = (unsigned short*)(ws + (size_t)NSUPP * KD * 2);
  // ws use: 50176*512*2 + 2048*512*2 = 53.5 MB

  prep_kernel<<<(NSUPP + NQRY) / 4, 256, 0, stream>>>(sup, qry, s_bf, q_bf);

  gemm_kernel<<<6272, 256, 0, stream>>>(s_bf, q_bf, out);
}